// Round 10
// baseline (106.007 us; speedup 1.0000x reference)
//
#include <hip/hip_runtime.h>
#include <math.h>

// ---------------------------------------------------------------------------
// CurriculumLoss: l_count + t*(OT via Sinkhorn on 64x64 downsample) + t*TV
//
// K = exp(-M/0.05) underflows to 0 in f32 for M >= 8; the surviving 9-tap
// kernel is exactly separable: (1, e^-20) (x) (1, e^-20). Sinkhorn becomes
// 100 half-steps of a separable 3x3 stencil + rcp on a 64x64 field.
//
// R10 = R9 (redundant-halo time skewing) with the NaN fixed:
//  - R9's pad-column guard was fmaxf(d, 1e-38f); 1e-38 is DENORMAL, and
//    v_rcp_f32 flushes denormal inputs -> rcp(1e-38)=+inf -> 0*inf=NaN in
//    the pad columns, which then leaked in-field via the horizontal window.
//    Guard is now 1e-30f (normal): rcp(1e-30)=1e30 finite, cf=0 in pads ->
//    pads stay exactly 0. In-field d >= ~1e-12 >> 1e-30 -> guard never
//    engages in-field -> arithmetic bit-identical to R8.
//  - lane = row (64 lanes), wave w of 4 owns cols [16w,16w+15] + 4-col halo
//    each side (24-col register arrays). 4 half-steps per seam exchange with
//    shrinking windows [1,22]u -> [2,21]v -> [3,20]u -> [4,19]v, then one
//    4-col/side exchange (2x ds_write_b128 + 2x ds_read_b128, double-
//    buffered) + ONE barrier. Barriers: 100 -> 25. Redundant VALU: +19%.
//  - Vertical 3-tap via whole-wave DPP wave_shr/shl (zero-fill = boundary).
//  - prep_kernel (full-chip pooling+TV) and ticket finalize kept from R8.
//
// ws layout (floats):
//   [0..256) pc partials   [256..512) gc partials
//   [512..768) tvx         [768..1024) tvy
//   [1024..1040) cost per image ; cnt dword at byte 4160
//   [2048..67584) pooled pred fields (16 x 4096) ; [67584..133120) gt fields
// ---------------------------------------------------------------------------

#define KW1 2.0611536224385578e-09f  // exp(-20)
#define MW2 8.4967085105831778e-18f  // 2*exp(-40)
#define RP2 72
#define PDOFF 2048
#define GDOFF 67584

// 16-lane-row DPP shifts (used by prep/fallback)
__device__ __forceinline__ float dpp_right(float x) {  // lane tx+1's value; 0 at tx==15
  return __int_as_float(__builtin_amdgcn_update_dpp(
      0, __float_as_int(x), 0x101, 0xF, 0xF, true));
}
__device__ __forceinline__ float dpp_left(float x) {
  return __int_as_float(__builtin_amdgcn_update_dpp(
      0, __float_as_int(x), 0x111, 0xF, 0xF, true));
}
// whole-wave shifts: vertical neighbors in the row-per-lane layout
__device__ __forceinline__ float wshr1(float x) {  // lane i <- lane i-1; 0 into lane 0
  return __int_as_float(__builtin_amdgcn_update_dpp(
      0, __float_as_int(x), 0x138, 0xF, 0xF, true));  // wave_shr:1
}
__device__ __forceinline__ float wshl1(float x) {  // lane i <- lane i+1; 0 into lane 63
  return __int_as_float(__builtin_amdgcn_update_dpp(
      0, __float_as_int(x), 0x130, 0xF, 0xF, true));  // wave_shl:1
}

__device__ __forceinline__ float ad4(const float4 a, const float4 b) {
  return fabsf(a.x - b.x) + fabsf(a.y - b.y) + fabsf(a.z - b.z) + fabsf(a.w - b.w);
}
__device__ __forceinline__ float agent_ld(const float* p) {
  return __hip_atomic_load(p, __ATOMIC_RELAXED, __HIP_MEMORY_SCOPE_AGENT);
}

// One half-step over column window [LO,HI]: dst = cf * rcp(K_3x3 * src).
// src must be valid on [LO-1, HI+1]. Vertical halos via whole-wave DPP.
// Guard 1e-30f (NORMAL float): engages only at out-of-field pad columns
// where d == 0 exactly (cf == 0 there -> dst = 0 exactly).
template <int LO, int HI>
__device__ __forceinline__ void half_phase(const float (&src)[24],
                                           const float (&cf)[24],
                                           float (&dst)[24], float (&hh)[24]) {
#pragma unroll
  for (int i = LO; i <= HI; ++i)
    hh[i] = fmaf(KW1, src[i - 1] + src[i + 1], src[i]);
#pragma unroll
  for (int i = LO; i <= HI; ++i) {
    const float d = fmaf(KW1, wshr1(hh[i]) + wshl1(hh[i]), hh[i]);
    dst[i] = cf[i] * __builtin_amdgcn_rcpf(fmaxf(d, 1e-30f));
  }
}

// ======================= prep: full-chip pooling + TV =======================
__global__ __launch_bounds__(256) void prep_kernel(
    const float* __restrict__ pred, const float* __restrict__ gt,
    float* __restrict__ ws) {
  __shared__ float rbuf[16];
  const int g = blockIdx.x;
  const int im = g >> 4, band = g & 15;
  const int t = threadIdx.x;
  const int ppy = t >> 6, ppx = t & 63;
  const float* pb = pred + im * 65536;
  const float* gb = gt + im * 65536;
  const int sr0 = band * 16 + ppy * 4;
  const int c0 = ppx * 4;

  float4 q[4];
  float ps = 0.f, gs = 0.f, sx = 0.f, sy = 0.f;
#pragma unroll
  for (int r = 0; r < 4; ++r) {
    q[r] = *(const float4*)(pb + (sr0 + r) * 256 + c0);
    const float4 e = *(const float4*)(gb + (sr0 + r) * 256 + c0);
    ps += (q[r].x + q[r].y) + (q[r].z + q[r].w);
    gs += (e.x + e.y) + (e.z + e.w);
    sx += fabsf(q[r].y - q[r].x) + fabsf(q[r].z - q[r].y) + fabsf(q[r].w - q[r].z);
    const float nf = __shfl_down(q[r].x, 1);
    if (ppx < 63) sx += fabsf(nf - q[r].w);
  }
  sy += ad4(q[1], q[0]) + ad4(q[2], q[1]) + ad4(q[3], q[2]);
  if (sr0 + 4 < 256) {
    const float4 qn = *(const float4*)(pb + (sr0 + 4) * 256 + c0);
    sy += ad4(qn, q[3]);
  }
  const int prow = band * 4 + ppy;
  ws[PDOFF + im * 4096 + prow * 64 + ppx] = fmaxf(ps * 0.0625f, 0.f);
  ws[GDOFF + im * 4096 + prow * 64 + ppx] = fmaxf(gs * 0.0625f, 0.f);

  float r0 = ps, r1 = gs, r2 = sx, r3 = sy;
#pragma unroll
  for (int o = 32; o > 0; o >>= 1) {
    r0 += __shfl_down(r0, o); r1 += __shfl_down(r1, o);
    r2 += __shfl_down(r2, o); r3 += __shfl_down(r3, o);
  }
  if ((t & 63) == 0) {
    const int w = t >> 6;
    rbuf[w * 4 + 0] = r0; rbuf[w * 4 + 1] = r1;
    rbuf[w * 4 + 2] = r2; rbuf[w * 4 + 3] = r3;
  }
  __syncthreads();
  if (t == 0) {
    float a0 = 0, a1 = 0, a2 = 0, a3 = 0;
    for (int w = 0; w < 4; ++w) {
      a0 += rbuf[w * 4]; a1 += rbuf[w * 4 + 1];
      a2 += rbuf[w * 4 + 2]; a3 += rbuf[w * 4 + 3];
    }
    ws[g] = a0; ws[256 + g] = a1; ws[512 + g] = a2; ws[768 + g] = a3;
  }
}

// ============ sinkhorn: row-per-lane layout + redundant halo ================
__global__ __launch_bounds__(256) void sink_kernel(
    float* __restrict__ ws, const int* __restrict__ epoch,
    const int* __restrict__ max_epoch, float* __restrict__ out,
    unsigned int* __restrict__ cnt) {
  // seam buffers: [parity][slot 0..5][lane][4 cols]; slots 0,5 = zero guards
  __shared__ float SL[2][6 * 256], SR[2][6 * 256];
  __shared__ float rbuf[24];
  __shared__ int lastflag;

  const int b = blockIdx.x;
  const int t = threadIdx.x;
  const int w = t >> 6;          // wave = 16-col slice
  const int l = t & 63;          // lane = row
  const int colbase = 16 * w - 4;

  for (int i = t; i < 6 * 256; i += 256) {
    SL[0][i] = 0.f; SR[0][i] = 0.f; SL[1][i] = 0.f; SR[1][i] = 0.f;
  }

  // load a,b over the 24-col extended slice (zeros out of field)
  float av[24], bv[24];
  const float* P = &ws[PDOFF + b * 4096 + l * 64];
  const float* G = &ws[GDOFF + b * 4096 + l * 64];
#pragma unroll
  for (int k = 0; k < 6; ++k) {
    const int c0 = colbase + 4 * k;   // wave-uniform condition
    if (c0 >= 0 && c0 <= 60) {
      const float4 qa = *(const float4*)(P + c0);
      av[4 * k] = qa.x; av[4 * k + 1] = qa.y;
      av[4 * k + 2] = qa.z; av[4 * k + 3] = qa.w;
      const float4 qb = *(const float4*)(G + c0);
      bv[4 * k] = qb.x; bv[4 * k + 1] = qb.y;
      bv[4 * k + 2] = qb.z; bv[4 * k + 3] = qb.w;
    } else {
      av[4 * k] = 0.f; av[4 * k + 1] = 0.f; av[4 * k + 2] = 0.f; av[4 * k + 3] = 0.f;
      bv[4 * k] = 0.f; bv[4 * k + 1] = 0.f; bv[4 * k + 2] = 0.f; bv[4 * k + 3] = 0.f;
    }
  }
  float spd = 0.f, sgd = 0.f;
#pragma unroll
  for (int i = 4; i < 20; ++i) { spd += av[i]; sgd += bv[i]; }  // own cols only
#pragma unroll
  for (int o = 32; o > 0; o >>= 1) {
    spd += __shfl_down(spd, o); sgd += __shfl_down(sgd, o);
  }
  if (l == 0) { rbuf[w * 2] = spd; rbuf[w * 2 + 1] = sgd; }
  __syncthreads();  // also covers SL/SR zero-init
  const float Sp = rbuf[0] + rbuf[2] + rbuf[4] + rbuf[6];
  const float Sg = rbuf[1] + rbuf[3] + rbuf[5] + rbuf[7];

  float vv[24], uu[24], hh[24];
#pragma unroll
  for (int i = 0; i < 24; ++i) {
    const bool infld = (unsigned)(colbase + i) < 64u;
    av[i] = infld ? ((Sp > 0.f) ? (av[i] / Sp) : (1.f / 4096.f)) : 0.f;
    bv[i] = infld ? ((Sg > 0.f) ? (bv[i] / Sg) : (1.f / 4096.f)) : 0.f;
    vv[i] = infld ? 1.f : 0.f;   // v init = ones in field, 0 in pad
    uu[i] = 0.f; hh[i] = 0.f;
  }

  // 25 periods x (4 half-steps + 1 exchange + 1 barrier) = 50 iterations
#pragma unroll 1
  for (int p = 0; p < 25; ++p) {
    half_phase<1, 22>(vv, av, uu, hh);   // u = a/(Kv)
    half_phase<2, 21>(uu, bv, vv, hh);   // v = b/(Ku)
    half_phase<3, 20>(vv, av, uu, hh);
    half_phase<4, 19>(uu, bv, vv, hh);
    float* sl = SL[p & 1];
    float* sr = SR[p & 1];
    *(float4*)&sl[(w + 1) * 256 + l * 4] = make_float4(vv[4], vv[5], vv[6], vv[7]);
    *(float4*)&sr[(w + 1) * 256 + l * 4] = make_float4(vv[16], vv[17], vv[18], vv[19]);
    __syncthreads();
    const float4 Lh = *(const float4*)&sr[w * 256 + l * 4];        // slot0=zeros
    const float4 Rh = *(const float4*)&sl[(w + 2) * 256 + l * 4];  // slot5=zeros
    vv[0] = Lh.x; vv[1] = Lh.y; vv[2] = Lh.z; vv[3] = Lh.w;
    vv[20] = Rh.x; vv[21] = Rh.y; vv[22] = Rh.z; vv[23] = Rh.w;
  }

  // ---- cost = sum u * ((K.M) v): edges KW1, corners 2e^-40 ----
  // vv valid on [0..23] (final exchange), uu on [3..20].
  float c = 0.f;
#pragma unroll
  for (int cc = 4; cc < 20; ++cc) {
    const float s = vv[cc - 1] + vv[cc + 1];
    const float e = (wshr1(vv[cc]) + wshl1(vv[cc])) + s;
    const float d = wshr1(s) + wshl1(s);
    c += uu[cc] * fmaf(MW2, d, KW1 * e);
  }
#pragma unroll
  for (int o = 32; o > 0; o >>= 1) c += __shfl_down(c, o);
  if (l == 0) rbuf[8 + w] = c;
  __syncthreads();
  if (t == 0) {
    ws[1024 + b] = rbuf[8] + rbuf[9] + rbuf[10] + rbuf[11];
    __threadfence();
    const unsigned int old = atomicAdd(cnt, 1u);
    lastflag = (old == 15u) ? 1 : 0;
  }
  __syncthreads();

  // ---- cooperative finalize by the last block ----
  if (lastflag) {
    __threadfence();
    float myPc = agent_ld(&ws[t]);
    float myGc = agent_ld(&ws[256 + t]);
    float myTx = agent_ld(&ws[512 + t]);
    float myTy = agent_ld(&ws[768 + t]);
#pragma unroll
    for (int o = 8; o > 0; o >>= 1) {
      myPc += __shfl_down(myPc, o, 16);
      myGc += __shfl_down(myGc, o, 16);
    }
    float d = ((t & 15) == 0) ? fabsf(myPc - myGc) : 0.f;
    float ct = (t < 16) ? agent_ld(&ws[1024 + t]) : 0.f;
#pragma unroll
    for (int o = 32; o > 0; o >>= 1) {
      d += __shfl_down(d, o); ct += __shfl_down(ct, o);
      myTx += __shfl_down(myTx, o); myTy += __shfl_down(myTy, o);
    }
    if ((t & 63) == 0) {
      const int ww = t >> 6;
      rbuf[ww * 4] = d; rbuf[ww * 4 + 1] = ct;
      rbuf[ww * 4 + 2] = myTx; rbuf[ww * 4 + 3] = myTy;
    }
    __syncthreads();
    if (t == 0) {
      float lc = 0, lot = 0, tvx = 0, tvy = 0;
      for (int ww = 0; ww < 4; ++ww) {
        lc += rbuf[ww * 4]; lot += rbuf[ww * 4 + 1];
        tvx += rbuf[ww * 4 + 2]; tvy += rbuf[ww * 4 + 3];
      }
      int me = max_epoch[0]; if (me < 1) me = 1;
      const float tt = (float)epoch[0] / (float)me;
      const float ltv = tvx / (16.f * 256.f * 255.f) + tvy / (16.f * 255.f * 256.f);
      out[0] = lc * (1.f / 16.f) + tt * (lot * (1.f / 16.f)) + tt * ltv;
    }
  }
}

// ================= fallback (R6 monolith) if ws is too small ================
__device__ __forceinline__ void hrow4(const float f[4], float h[4]) {
  const float l = dpp_left(f[3]);
  const float r = dpp_right(f[0]);
  h[0] = fmaf(KW1, l + f[1], f[0]);
  h[1] = fmaf(KW1, f[0] + f[2], f[1]);
  h[2] = fmaf(KW1, f[1] + f[3], f[2]);
  h[3] = fmaf(KW1, f[2] + r, f[3]);
}
__device__ __forceinline__ void phase_core(
    const float prev[4][4], float ph[4][4],
    const float cf0[4], const float cf3[4],
    float2 mA, float4 mB, float2 mC, float2 pA, float4 pB, float2 pC,
    float* __restrict__ RT_wr, float* __restrict__ RB_wr, int wb,
    float out0[4], float out3[4]) {
  hrow4(prev[0], ph[0]); hrow4(prev[1], ph[1]);
  hrow4(prev[2], ph[2]); hrow4(prev[3], ph[3]);
  float hm[4], hp[4];
  hm[0] = fmaf(KW1, mA.y + mB.y, mB.x);
  hm[1] = fmaf(KW1, mB.x + mB.z, mB.y);
  hm[2] = fmaf(KW1, mB.y + mB.w, mB.z);
  hm[3] = fmaf(KW1, mB.z + mC.x, mB.w);
  hp[0] = fmaf(KW1, pA.y + pB.y, pB.x);
  hp[1] = fmaf(KW1, pB.x + pB.z, pB.y);
  hp[2] = fmaf(KW1, pB.y + pB.w, pB.z);
  hp[3] = fmaf(KW1, pB.z + pC.x, pB.w);
#pragma unroll
  for (int j = 0; j < 4; ++j)
    out0[j] = cf0[j] * __builtin_amdgcn_rcpf(fmaf(KW1, hm[j] + ph[1][j], ph[0][j]));
#pragma unroll
  for (int j = 0; j < 4; ++j)
    out3[j] = cf3[j] * __builtin_amdgcn_rcpf(fmaf(KW1, ph[2][j] + hp[j], ph[3][j]));
  *(float4*)&RT_wr[wb] = make_float4(out0[0], out0[1], out0[2], out0[3]);
  *(float4*)&RB_wr[wb] = make_float4(out3[0], out3[1], out3[2], out3[3]);
}

__global__ __launch_bounds__(256) void fused_fallback(
    const float* __restrict__ pred, const float* __restrict__ gt,
    float* __restrict__ ws, const int* __restrict__ epoch,
    const int* __restrict__ max_epoch, float* __restrict__ out,
    unsigned int* __restrict__ cnt) {
  __shared__ float RTu[18 * RP2], RBu[18 * RP2];
  __shared__ float RTv[18 * RP2], RBv[18 * RP2];
  __shared__ float rbuf[24];

  const int b = blockIdx.x;
  const int t = threadIdx.x;
  const int tyg = t >> 4, tx = t & 15;
  const int y0 = tyg * 4, x0 = tx * 4;

  for (int i = t; i < 18 * RP2; i += 256) {
    RTu[i] = 0.f; RBu[i] = 0.f; RTv[i] = 0.f; RBv[i] = 0.f;
  }

  const float* pb = pred + b * 65536;
  const float* gb = gt + b * 65536;
  const int sr0 = 4 * y0, sc0 = 4 * x0;

  float pd[4][4], gd[4][4];
  float4 pr0, pr1, pr2, pr3;
  float spraw = 0.f, sgraw = 0.f, sx = 0.f, sy = 0.f;
#pragma unroll
  for (int i = 0; i < 4; ++i) {
    float a0 = 0.f, a1 = 0.f, a2 = 0.f, a3 = 0.f;
    float c0 = 0.f, c1 = 0.f, c2 = 0.f, c3 = 0.f;
#pragma unroll 1
    for (int rr = 0; rr < 4; ++rr) {
      const int r = i * 4 + rr;
      const float* prow = pb + (sr0 + r) * 256 + sc0;
      const float4 q0 = *(const float4*)(prow);
      const float4 q1 = *(const float4*)(prow + 4);
      const float4 q2 = *(const float4*)(prow + 8);
      const float4 q3 = *(const float4*)(prow + 12);
      const float s0 = (q0.x + q0.y) + (q0.z + q0.w);
      const float s1 = (q1.x + q1.y) + (q1.z + q1.w);
      const float s2 = (q2.x + q2.y) + (q2.z + q2.w);
      const float s3 = (q3.x + q3.y) + (q3.z + q3.w);
      a0 += s0; a1 += s1; a2 += s2; a3 += s3;
      spraw += (s0 + s1) + (s2 + s3);
      sx += fabsf(q0.y - q0.x) + fabsf(q0.z - q0.y) + fabsf(q0.w - q0.z)
          + fabsf(q1.x - q0.w)
          + fabsf(q1.y - q1.x) + fabsf(q1.z - q1.y) + fabsf(q1.w - q1.z)
          + fabsf(q2.x - q1.w)
          + fabsf(q2.y - q2.x) + fabsf(q2.z - q2.y) + fabsf(q2.w - q2.z)
          + fabsf(q3.x - q2.w)
          + fabsf(q3.y - q3.x) + fabsf(q3.z - q3.y) + fabsf(q3.w - q3.z);
      const float nf = dpp_right(q0.x);
      if (tx < 15) sx += fabsf(nf - q3.w);
      if (r > 0) sy += ad4(q0, pr0) + ad4(q1, pr1) + ad4(q2, pr2) + ad4(q3, pr3);
      pr0 = q0; pr1 = q1; pr2 = q2; pr3 = q3;
      const float* grow = gb + (sr0 + r) * 256 + sc0;
      const float4 g0 = *(const float4*)(grow);
      const float4 g1 = *(const float4*)(grow + 4);
      const float4 g2 = *(const float4*)(grow + 8);
      const float4 g3 = *(const float4*)(grow + 12);
      const float u0 = (g0.x + g0.y) + (g0.z + g0.w);
      const float u1 = (g1.x + g1.y) + (g1.z + g1.w);
      const float u2 = (g2.x + g2.y) + (g2.z + g2.w);
      const float u3 = (g3.x + g3.y) + (g3.z + g3.w);
      c0 += u0; c1 += u1; c2 += u2; c3 += u3;
      sgraw += (u0 + u1) + (u2 + u3);
    }
    pd[i][0] = a0; pd[i][1] = a1; pd[i][2] = a2; pd[i][3] = a3;
    gd[i][0] = c0; gd[i][1] = c1; gd[i][2] = c2; gd[i][3] = c3;
  }
  if (tyg < 15) {
    const float* prow = pb + (sr0 + 16) * 256 + sc0;
    sy += ad4(*(const float4*)(prow), pr0) + ad4(*(const float4*)(prow + 4), pr1)
        + ad4(*(const float4*)(prow + 8), pr2) + ad4(*(const float4*)(prow + 12), pr3);
  }

  float spd = 0.f, sgd = 0.f;
#pragma unroll
  for (int i = 0; i < 4; ++i)
#pragma unroll
    for (int j = 0; j < 4; ++j) {
      pd[i][j] = fmaxf(pd[i][j] * 0.0625f, 0.f); spd += pd[i][j];
      gd[i][j] = fmaxf(gd[i][j] * 0.0625f, 0.f); sgd += gd[i][j];
    }

  float r0 = spraw, r1 = sgraw, r2 = spd, r3 = sgd, r4 = sx, r5 = sy;
#pragma unroll
  for (int o = 32; o > 0; o >>= 1) {
    r0 += __shfl_down(r0, o); r1 += __shfl_down(r1, o);
    r2 += __shfl_down(r2, o); r3 += __shfl_down(r3, o);
    r4 += __shfl_down(r4, o); r5 += __shfl_down(r5, o);
  }
  if ((t & 63) == 0) {
    const int w = t >> 6;
    rbuf[w * 6 + 0] = r0; rbuf[w * 6 + 1] = r1; rbuf[w * 6 + 2] = r2;
    rbuf[w * 6 + 3] = r3; rbuf[w * 6 + 4] = r4; rbuf[w * 6 + 5] = r5;
  }
  __syncthreads();
  if (t == 0) {
    float a0 = 0, a1 = 0, a2 = 0, a3 = 0, a4 = 0, a5 = 0;
    for (int w = 0; w < 4; ++w) {
      a0 += rbuf[w * 6 + 0]; a1 += rbuf[w * 6 + 1]; a2 += rbuf[w * 6 + 2];
      a3 += rbuf[w * 6 + 3]; a4 += rbuf[w * 6 + 4]; a5 += rbuf[w * 6 + 5];
    }
    ws[b] = a0; ws[16 + b] = a1; ws[48 + b] = a4; ws[64 + b] = a5;
    rbuf[0] = a2; rbuf[1] = a3;
  }
  __syncthreads();
  const float Sp = rbuf[0], Sg = rbuf[1];

  float av[4][4], bv[4][4];
#pragma unroll
  for (int i = 0; i < 4; ++i)
#pragma unroll
    for (int j = 0; j < 4; ++j) {
      av[i][j] = (Sp > 0.f) ? (pd[i][j] / Sp) : (1.f / 4096.f);
      bv[i][j] = (Sg > 0.f) ? (gd[i][j] / Sg) : (1.f / 4096.f);
    }

  const int rbb = tyg * RP2 + x0 + 2;
  const int rtb = (tyg + 2) * RP2 + x0 + 2;
  const int wb  = (1 + tyg) * RP2 + 4 + x0;

  float uu[4][4], vv[4][4], uh[4][4], vh[4][4];
#pragma unroll
  for (int i = 0; i < 4; ++i)
#pragma unroll
    for (int j = 0; j < 4; ++j) vv[i][j] = 1.f;
  *(float4*)&RTv[wb] = make_float4(1.f, 1.f, 1.f, 1.f);
  *(float4*)&RBv[wb] = make_float4(1.f, 1.f, 1.f, 1.f);
  __syncthreads();

#pragma unroll 1
  for (int it = 0; it < 50; ++it) {
    {
      const float2 mA = *(const float2*)&RBv[rbb];
      const float4 mB = *(const float4*)&RBv[rbb + 2];
      const float2 mC = *(const float2*)&RBv[rbb + 6];
      const float2 pA = *(const float2*)&RTv[rtb];
      const float4 pB = *(const float4*)&RTv[rtb + 2];
      const float2 pC = *(const float2*)&RTv[rtb + 6];
      if (it != 0) {
#pragma unroll
        for (int j = 0; j < 4; ++j) {
          vv[1][j] = bv[1][j] * __builtin_amdgcn_rcpf(fmaf(KW1, uh[0][j] + uh[2][j], uh[1][j]));
          vv[2][j] = bv[2][j] * __builtin_amdgcn_rcpf(fmaf(KW1, uh[1][j] + uh[3][j], uh[2][j]));
        }
      }
      phase_core(vv, vh, av[0], av[3], mA, mB, mC, pA, pB, pC,
                 RTu, RBu, wb, uu[0], uu[3]);
    }
    __syncthreads();
    {
      const float2 mA = *(const float2*)&RBu[rbb];
      const float4 mB = *(const float4*)&RBu[rbb + 2];
      const float2 mC = *(const float2*)&RBu[rbb + 6];
      const float2 pA = *(const float2*)&RTu[rtb];
      const float4 pB = *(const float4*)&RTu[rtb + 2];
      const float2 pC = *(const float2*)&RTu[rtb + 6];
#pragma unroll
      for (int j = 0; j < 4; ++j) {
        uu[1][j] = av[1][j] * __builtin_amdgcn_rcpf(fmaf(KW1, vh[0][j] + vh[2][j], vh[1][j]));
        uu[2][j] = av[2][j] * __builtin_amdgcn_rcpf(fmaf(KW1, vh[1][j] + vh[3][j], vh[2][j]));
      }
      phase_core(uu, uh, bv[0], bv[3], mA, mB, mC, pA, pB, pC,
                 RTv, RBv, wb, vv[0], vv[3]);
    }
    __syncthreads();
  }
#pragma unroll
  for (int j = 0; j < 4; ++j) {
    vv[1][j] = bv[1][j] * __builtin_amdgcn_rcpf(fmaf(KW1, uh[0][j] + uh[2][j], uh[1][j]));
    vv[2][j] = bv[2][j] * __builtin_amdgcn_rcpf(fmaf(KW1, uh[1][j] + uh[3][j], uh[2][j]));
  }

  float c = 0.f;
  {
    const float2 mA = *(const float2*)&RBv[rbb];
    const float4 mB = *(const float4*)&RBv[rbb + 2];
    const float2 mC = *(const float2*)&RBv[rbb + 6];
    const float2 pA = *(const float2*)&RTv[rtb];
    const float4 pB = *(const float4*)&RTv[rtb + 2];
    const float2 pC = *(const float2*)&RTv[rtb + 6];
    float W[6][6];
    W[0][0] = mA.y; W[0][1] = mB.x; W[0][2] = mB.y;
    W[0][3] = mB.z; W[0][4] = mB.w; W[0][5] = mC.x;
    W[5][0] = pA.y; W[5][1] = pB.x; W[5][2] = pB.y;
    W[5][3] = pB.z; W[5][4] = pB.w; W[5][5] = pC.x;
#pragma unroll
    for (int i = 0; i < 4; ++i) {
      W[1 + i][0] = dpp_left(vv[i][3]);
      W[1 + i][5] = dpp_right(vv[i][0]);
#pragma unroll
      for (int j = 0; j < 4; ++j) W[1 + i][1 + j] = vv[i][j];
    }
#pragma unroll
    for (int i = 0; i < 4; ++i)
#pragma unroll
      for (int j = 0; j < 4; ++j) {
        const float e = (W[i][j + 1] + W[i + 2][j + 1])
                      + (W[i + 1][j] + W[i + 1][j + 2]);
        const float d = (W[i][j] + W[i][j + 2])
                      + (W[i + 2][j] + W[i + 2][j + 2]);
        c += uu[i][j] * fmaf(MW2, d, KW1 * e);
      }
  }
#pragma unroll
  for (int o = 32; o > 0; o >>= 1) c += __shfl_down(c, o);
  if ((t & 63) == 0) rbuf[t >> 6] = c;
  __syncthreads();
  if (t == 0) {
    ws[32 + b] = rbuf[0] + rbuf[1] + rbuf[2] + rbuf[3];
    __threadfence();
    const unsigned int old = atomicAdd(cnt, 1u);
    if (old == 15u) {
      __threadfence();
      float lc = 0.f, lot = 0.f, tvx = 0.f, tvy = 0.f;
      for (int k = 0; k < 16; ++k) {
        const float p = agent_ld(&ws[k]);
        const float g = agent_ld(&ws[16 + k]);
        const float ct = agent_ld(&ws[32 + k]);
        const float x = agent_ld(&ws[48 + k]);
        const float y = agent_ld(&ws[64 + k]);
        lc += fabsf(p - g); lot += ct; tvx += x; tvy += y;
      }
      int me = max_epoch[0]; if (me < 1) me = 1;
      const float tt = (float)epoch[0] / (float)me;
      const float ltv = tvx / (16.f * 256.f * 255.f) + tvy / (16.f * 255.f * 256.f);
      out[0] = lc * (1.f / 16.f) + tt * (lot * (1.f / 16.f)) + tt * ltv;
    }
  }
}

extern "C" void kernel_launch(void* const* d_in, const int* in_sizes, int n_in,
                              void* d_out, int out_size, void* d_ws, size_t ws_size,
                              hipStream_t stream) {
  const float* pred = (const float*)d_in[0];
  const float* gt   = (const float*)d_in[1];
  const int* epoch  = (const int*)d_in[2];
  const int* max_ep = (const int*)d_in[3];
  float* out = (float*)d_out;
  float* ws  = (float*)d_ws;

  if (ws_size >= 600000) {
    unsigned int* cnt = (unsigned int*)((char*)d_ws + 4160);
    hipMemsetAsync(cnt, 0, 4, stream);
    prep_kernel<<<dim3(256), dim3(256), 0, stream>>>(pred, gt, ws);
    sink_kernel<<<dim3(16), dim3(256), 0, stream>>>(ws, epoch, max_ep, out, cnt);
  } else {
    unsigned int* cnt = (unsigned int*)((char*)d_ws + 384);
    hipMemsetAsync(cnt, 0, 4, stream);
    fused_fallback<<<dim3(16), dim3(256), 0, stream>>>(pred, gt, ws, epoch,
                                                       max_ep, out, cnt);
  }
}

// Round 11
// 100.172 us; speedup vs baseline: 1.0583x; 1.0583x over previous
//
#include <hip/hip_runtime.h>
#include <math.h>

// ---------------------------------------------------------------------------
// CurriculumLoss: l_count + t*(OT via Sinkhorn on 64x64 downsample) + t*TV
//
// K = exp(-M/0.05) underflows to 0 in f32 for M >= 8; the surviving 9-tap
// kernel is exactly separable: (1, e^-20) (x) (1, e^-20). Sinkhorn becomes
// 100 half-steps of a separable 3x3 stencil + rcp on a 64x64 field.
//
// R11: ONE IMAGE ACROSS 16 WAVES (4 waves/SIMD). R10 falsified the barrier
// theory (4x fewer barriers -> slower); the floor is per-half-step latency
// (seam-read chain, DPP hazards, rcp latency) with nothing to hide it at
// 1 wave/SIMD. Fix: R8's structure but 1024 threads; wave w owns 4 columns.
// Per-wave issue/half-step drops ~4x and 4 waves/SIMD fill each other's
// hazard+LDS stalls. Arithmetic identical to R8 (absmax was 0.0).
//  - lane = row (64 lanes); vertical 3-tap via whole-wave DPP wave_shr/shl.
//  - Horizontal: hh in-register; seam cols exchanged via per-phase
//    double-buffered LDS slots (2x ds_write_b32 + 2x ds_read_b32 per
//    half-step per wave), slots 0/17 = zero guards. 2 barriers/iter.
//  - prep_kernel zeroes the ticket counter (memset dispatch removed).
//
// ws layout (floats):
//   [0..256) pc partials   [256..512) gc partials
//   [512..768) tvx         [768..1024) tvy
//   [1024..1040) cost per image ; cnt dword at byte 4160
//   [2048..67584) pooled pred fields (16 x 4096) ; [67584..133120) gt fields
// ---------------------------------------------------------------------------

#define KW1 2.0611536224385578e-09f  // exp(-20)
#define MW2 8.4967085105831778e-18f  // 2*exp(-40)
#define RP2 72
#define PDOFF 2048
#define GDOFF 67584

// 16-lane-row DPP shifts (used by prep/fallback)
__device__ __forceinline__ float dpp_right(float x) {  // lane tx+1's value; 0 at tx==15
  return __int_as_float(__builtin_amdgcn_update_dpp(
      0, __float_as_int(x), 0x101, 0xF, 0xF, true));
}
__device__ __forceinline__ float dpp_left(float x) {
  return __int_as_float(__builtin_amdgcn_update_dpp(
      0, __float_as_int(x), 0x111, 0xF, 0xF, true));
}
// whole-wave shifts: vertical neighbors in the row-per-lane layout
__device__ __forceinline__ float wshr1(float x) {  // lane i <- lane i-1; 0 into lane 0
  return __int_as_float(__builtin_amdgcn_update_dpp(
      0, __float_as_int(x), 0x138, 0xF, 0xF, true));  // wave_shr:1
}
__device__ __forceinline__ float wshl1(float x) {  // lane i <- lane i+1; 0 into lane 63
  return __int_as_float(__builtin_amdgcn_update_dpp(
      0, __float_as_int(x), 0x130, 0xF, 0xF, true));  // wave_shl:1
}

__device__ __forceinline__ float ad4(const float4 a, const float4 b) {
  return fabsf(a.x - b.x) + fabsf(a.y - b.y) + fabsf(a.z - b.z) + fabsf(a.w - b.w);
}
__device__ __forceinline__ float agent_ld(const float* p) {
  return __hip_atomic_load(p, __ATOMIC_RELAXED, __HIP_MEMORY_SCOPE_AGENT);
}

// ======================= prep: full-chip pooling + TV =======================
__global__ __launch_bounds__(256) void prep_kernel(
    const float* __restrict__ pred, const float* __restrict__ gt,
    float* __restrict__ ws, unsigned int* __restrict__ cnt) {
  __shared__ float rbuf[16];
  const int g = blockIdx.x;
  const int im = g >> 4, band = g & 15;
  const int t = threadIdx.x;
  if (g == 0 && t == 0) *cnt = 0u;   // replaces the memset dispatch
  const int ppy = t >> 6, ppx = t & 63;
  const float* pb = pred + im * 65536;
  const float* gb = gt + im * 65536;
  const int sr0 = band * 16 + ppy * 4;
  const int c0 = ppx * 4;

  float4 q[4];
  float ps = 0.f, gs = 0.f, sx = 0.f, sy = 0.f;
#pragma unroll
  for (int r = 0; r < 4; ++r) {
    q[r] = *(const float4*)(pb + (sr0 + r) * 256 + c0);
    const float4 e = *(const float4*)(gb + (sr0 + r) * 256 + c0);
    ps += (q[r].x + q[r].y) + (q[r].z + q[r].w);
    gs += (e.x + e.y) + (e.z + e.w);
    sx += fabsf(q[r].y - q[r].x) + fabsf(q[r].z - q[r].y) + fabsf(q[r].w - q[r].z);
    const float nf = __shfl_down(q[r].x, 1);
    if (ppx < 63) sx += fabsf(nf - q[r].w);
  }
  sy += ad4(q[1], q[0]) + ad4(q[2], q[1]) + ad4(q[3], q[2]);
  if (sr0 + 4 < 256) {
    const float4 qn = *(const float4*)(pb + (sr0 + 4) * 256 + c0);
    sy += ad4(qn, q[3]);
  }
  const int prow = band * 4 + ppy;
  ws[PDOFF + im * 4096 + prow * 64 + ppx] = fmaxf(ps * 0.0625f, 0.f);
  ws[GDOFF + im * 4096 + prow * 64 + ppx] = fmaxf(gs * 0.0625f, 0.f);

  float r0 = ps, r1 = gs, r2 = sx, r3 = sy;
#pragma unroll
  for (int o = 32; o > 0; o >>= 1) {
    r0 += __shfl_down(r0, o); r1 += __shfl_down(r1, o);
    r2 += __shfl_down(r2, o); r3 += __shfl_down(r3, o);
  }
  if ((t & 63) == 0) {
    const int w = t >> 6;
    rbuf[w * 4 + 0] = r0; rbuf[w * 4 + 1] = r1;
    rbuf[w * 4 + 2] = r2; rbuf[w * 4 + 3] = r3;
  }
  __syncthreads();
  if (t == 0) {
    float a0 = 0, a1 = 0, a2 = 0, a3 = 0;
    for (int w = 0; w < 4; ++w) {
      a0 += rbuf[w * 4]; a1 += rbuf[w * 4 + 1];
      a2 += rbuf[w * 4 + 2]; a3 += rbuf[w * 4 + 3];
    }
    ws[g] = a0; ws[256 + g] = a1; ws[512 + g] = a2; ws[768 + g] = a3;
  }
}

// ============ sinkhorn: row-per-lane, 16 waves per image ====================
__global__ __launch_bounds__(1024) void sink_kernel(
    float* __restrict__ ws, const int* __restrict__ epoch,
    const int* __restrict__ max_epoch, float* __restrict__ out,
    unsigned int* __restrict__ cnt) {
  // seam arrays: slot s in 0..17 (slots 0,17 = zero guards), own slot = w+1
  __shared__ float SuL[18 * 64], SuR[18 * 64], SvL[18 * 64], SvR[18 * 64];
  __shared__ float rbuf[40];
  __shared__ int lastflag;

  const int b = blockIdx.x;
  const int t = threadIdx.x;
  const int w = t >> 6;   // wave = 4-col slice, 0..15
  const int l = t & 63;   // lane = row

  for (int i = t; i < 18 * 64; i += 1024) {
    SuL[i] = 0.f; SuR[i] = 0.f; SvL[i] = 0.f; SvR[i] = 0.f;
  }

  // load pooled fields: my row l, cols 4w..4w+3 (L2-hot from prep)
  float av[4], bv[4];
  const float4 qa = *(const float4*)&ws[PDOFF + b * 4096 + l * 64 + 4 * w];
  const float4 qb = *(const float4*)&ws[GDOFF + b * 4096 + l * 64 + 4 * w];
  av[0] = qa.x; av[1] = qa.y; av[2] = qa.z; av[3] = qa.w;
  bv[0] = qb.x; bv[1] = qb.y; bv[2] = qb.z; bv[3] = qb.w;
  float spd = (qa.x + qa.y) + (qa.z + qa.w);
  float sgd = (qb.x + qb.y) + (qb.z + qb.w);
#pragma unroll
  for (int o = 32; o > 0; o >>= 1) {
    spd += __shfl_down(spd, o); sgd += __shfl_down(sgd, o);
  }
  if (l == 0) { rbuf[w * 2] = spd; rbuf[w * 2 + 1] = sgd; }
  __syncthreads();  // covers zero-init + rbuf
  float Sp = 0.f, Sg = 0.f;
#pragma unroll
  for (int k = 0; k < 16; ++k) { Sp += rbuf[2 * k]; Sg += rbuf[2 * k + 1]; }

#pragma unroll
  for (int j = 0; j < 4; ++j) {
    av[j] = (Sp > 0.f) ? (av[j] / Sp) : (1.f / 4096.f);
    bv[j] = (Sg > 0.f) ? (bv[j] / Sg) : (1.f / 4096.f);
  }

  const int rdL = w * 64 + l;        // left nbr's right seam (slot 0 = zeros)
  const int rdR = (w + 2) * 64 + l;  // right nbr's left seam (slot 17 = zeros)
  const int wr  = (w + 1) * 64 + l;

  float uu[4], vv[4] = {1.f, 1.f, 1.f, 1.f}, hh[4];
  SvL[wr] = 1.f; SvR[wr] = 1.f;      // after the zero-init barrier
  __syncthreads();                   // seam ones visible

#pragma unroll 1
  for (int it = 0; it < 50; ++it) {
    {  // u = a / (K v)
      const float xl = SvR[rdL];
      const float xr = SvL[rdR];
      hh[0] = fmaf(KW1, xl + vv[1], vv[0]);
      hh[1] = fmaf(KW1, vv[0] + vv[2], vv[1]);
      hh[2] = fmaf(KW1, vv[1] + vv[3], vv[2]);
      hh[3] = fmaf(KW1, vv[2] + xr, vv[3]);
#pragma unroll
      for (int c = 0; c < 4; ++c) {
        const float d = fmaf(KW1, wshr1(hh[c]) + wshl1(hh[c]), hh[c]);
        uu[c] = av[c] * __builtin_amdgcn_rcpf(d);
      }
      SuL[wr] = uu[0]; SuR[wr] = uu[3];
    }
    __syncthreads();
    {  // v = b / (K u)
      const float xl = SuR[rdL];
      const float xr = SuL[rdR];
      hh[0] = fmaf(KW1, xl + uu[1], uu[0]);
      hh[1] = fmaf(KW1, uu[0] + uu[2], uu[1]);
      hh[2] = fmaf(KW1, uu[1] + uu[3], uu[2]);
      hh[3] = fmaf(KW1, uu[2] + xr, uu[3]);
#pragma unroll
      for (int c = 0; c < 4; ++c) {
        const float d = fmaf(KW1, wshr1(hh[c]) + wshl1(hh[c]), hh[c]);
        vv[c] = bv[c] * __builtin_amdgcn_rcpf(d);
      }
      SvL[wr] = vv[0]; SvR[wr] = vv[3];
    }
    __syncthreads();
  }

  // ---- cost = sum u * ((K.M) v): edges KW1, corners 2e^-40 ----
  float c = 0.f;
  {
    const float xl = SvR[rdL];  // final v seams (barrier above)
    const float xr = SvL[rdR];
#pragma unroll
    for (int cc = 0; cc < 4; ++cc) {
      const float vl = (cc == 0) ? xl : vv[cc - 1];
      const float vr = (cc == 3) ? xr : vv[cc + 1];
      const float s = vl + vr;                       // horizontal pair
      const float e = (wshr1(vv[cc]) + wshl1(vv[cc])) + s;
      const float d = wshr1(s) + wshl1(s);           // 4 corners
      c += uu[cc] * fmaf(MW2, d, KW1 * e);
    }
  }
#pragma unroll
  for (int o = 32; o > 0; o >>= 1) c += __shfl_down(c, o);
  if (l == 0) rbuf[w] = c;   // safe: Sp region consumed pre-loop, barriers since
  __syncthreads();
  if (t == 0) {
    float s = 0.f;
    for (int k = 0; k < 16; ++k) s += rbuf[k];
    ws[1024 + b] = s;
    __threadfence();
    const unsigned int old = atomicAdd(cnt, 1u);
    lastflag = (old == 15u) ? 1 : 0;
  }
  __syncthreads();

  // ---- cooperative finalize by the last block (first 256 threads load) ----
  if (lastflag) {
    __threadfence();
    float myPc = 0.f, myGc = 0.f, myTx = 0.f, myTy = 0.f;
    if (t < 256) {
      myPc = agent_ld(&ws[t]);
      myGc = agent_ld(&ws[256 + t]);
      myTx = agent_ld(&ws[512 + t]);
      myTy = agent_ld(&ws[768 + t]);
    }
#pragma unroll
    for (int o = 8; o > 0; o >>= 1) {  // per-image partial groups of 16
      myPc += __shfl_down(myPc, o, 16);
      myGc += __shfl_down(myGc, o, 16);
    }
    float d = ((t & 15) == 0) ? fabsf(myPc - myGc) : 0.f;
    float ct = (t < 16) ? agent_ld(&ws[1024 + t]) : 0.f;
#pragma unroll
    for (int o = 32; o > 0; o >>= 1) {
      d += __shfl_down(d, o); ct += __shfl_down(ct, o);
      myTx += __shfl_down(myTx, o); myTy += __shfl_down(myTy, o);
    }
    if ((t & 63) == 0 && t < 256) {
      const int ww = t >> 6;
      rbuf[16 + ww * 4] = d; rbuf[16 + ww * 4 + 1] = ct;
      rbuf[16 + ww * 4 + 2] = myTx; rbuf[16 + ww * 4 + 3] = myTy;
    }
    __syncthreads();
    if (t == 0) {
      float lc = 0, lot = 0, tvx = 0, tvy = 0;
      for (int ww = 0; ww < 4; ++ww) {
        lc += rbuf[16 + ww * 4]; lot += rbuf[16 + ww * 4 + 1];
        tvx += rbuf[16 + ww * 4 + 2]; tvy += rbuf[16 + ww * 4 + 3];
      }
      int me = max_epoch[0]; if (me < 1) me = 1;
      const float tt = (float)epoch[0] / (float)me;
      const float ltv = tvx / (16.f * 256.f * 255.f) + tvy / (16.f * 255.f * 256.f);
      out[0] = lc * (1.f / 16.f) + tt * (lot * (1.f / 16.f)) + tt * ltv;
    }
  }
}

// ================= fallback (R6 monolith) if ws is too small ================
__device__ __forceinline__ void hrow4(const float f[4], float h[4]) {
  const float l = dpp_left(f[3]);
  const float r = dpp_right(f[0]);
  h[0] = fmaf(KW1, l + f[1], f[0]);
  h[1] = fmaf(KW1, f[0] + f[2], f[1]);
  h[2] = fmaf(KW1, f[1] + f[3], f[2]);
  h[3] = fmaf(KW1, f[2] + r, f[3]);
}
__device__ __forceinline__ void phase_core(
    const float prev[4][4], float ph[4][4],
    const float cf0[4], const float cf3[4],
    float2 mA, float4 mB, float2 mC, float2 pA, float4 pB, float2 pC,
    float* __restrict__ RT_wr, float* __restrict__ RB_wr, int wb,
    float out0[4], float out3[4]) {
  hrow4(prev[0], ph[0]); hrow4(prev[1], ph[1]);
  hrow4(prev[2], ph[2]); hrow4(prev[3], ph[3]);
  float hm[4], hp[4];
  hm[0] = fmaf(KW1, mA.y + mB.y, mB.x);
  hm[1] = fmaf(KW1, mB.x + mB.z, mB.y);
  hm[2] = fmaf(KW1, mB.y + mB.w, mB.z);
  hm[3] = fmaf(KW1, mB.z + mC.x, mB.w);
  hp[0] = fmaf(KW1, pA.y + pB.y, pB.x);
  hp[1] = fmaf(KW1, pB.x + pB.z, pB.y);
  hp[2] = fmaf(KW1, pB.y + pB.w, pB.z);
  hp[3] = fmaf(KW1, pB.z + pC.x, pB.w);
#pragma unroll
  for (int j = 0; j < 4; ++j)
    out0[j] = cf0[j] * __builtin_amdgcn_rcpf(fmaf(KW1, hm[j] + ph[1][j], ph[0][j]));
#pragma unroll
  for (int j = 0; j < 4; ++j)
    out3[j] = cf3[j] * __builtin_amdgcn_rcpf(fmaf(KW1, ph[2][j] + hp[j], ph[3][j]));
  *(float4*)&RT_wr[wb] = make_float4(out0[0], out0[1], out0[2], out0[3]);
  *(float4*)&RB_wr[wb] = make_float4(out3[0], out3[1], out3[2], out3[3]);
}

__global__ __launch_bounds__(256) void fused_fallback(
    const float* __restrict__ pred, const float* __restrict__ gt,
    float* __restrict__ ws, const int* __restrict__ epoch,
    const int* __restrict__ max_epoch, float* __restrict__ out,
    unsigned int* __restrict__ cnt) {
  __shared__ float RTu[18 * RP2], RBu[18 * RP2];
  __shared__ float RTv[18 * RP2], RBv[18 * RP2];
  __shared__ float rbuf[24];

  const int b = blockIdx.x;
  const int t = threadIdx.x;
  const int tyg = t >> 4, tx = t & 15;
  const int y0 = tyg * 4, x0 = tx * 4;

  for (int i = t; i < 18 * RP2; i += 256) {
    RTu[i] = 0.f; RBu[i] = 0.f; RTv[i] = 0.f; RBv[i] = 0.f;
  }

  const float* pb = pred + b * 65536;
  const float* gb = gt + b * 65536;
  const int sr0 = 4 * y0, sc0 = 4 * x0;

  float pd[4][4], gd[4][4];
  float4 pr0, pr1, pr2, pr3;
  float spraw = 0.f, sgraw = 0.f, sx = 0.f, sy = 0.f;
#pragma unroll
  for (int i = 0; i < 4; ++i) {
    float a0 = 0.f, a1 = 0.f, a2 = 0.f, a3 = 0.f;
    float c0 = 0.f, c1 = 0.f, c2 = 0.f, c3 = 0.f;
#pragma unroll 1
    for (int rr = 0; rr < 4; ++rr) {
      const int r = i * 4 + rr;
      const float* prow = pb + (sr0 + r) * 256 + sc0;
      const float4 q0 = *(const float4*)(prow);
      const float4 q1 = *(const float4*)(prow + 4);
      const float4 q2 = *(const float4*)(prow + 8);
      const float4 q3 = *(const float4*)(prow + 12);
      const float s0 = (q0.x + q0.y) + (q0.z + q0.w);
      const float s1 = (q1.x + q1.y) + (q1.z + q1.w);
      const float s2 = (q2.x + q2.y) + (q2.z + q2.w);
      const float s3 = (q3.x + q3.y) + (q3.z + q3.w);
      a0 += s0; a1 += s1; a2 += s2; a3 += s3;
      spraw += (s0 + s1) + (s2 + s3);
      sx += fabsf(q0.y - q0.x) + fabsf(q0.z - q0.y) + fabsf(q0.w - q0.z)
          + fabsf(q1.x - q0.w)
          + fabsf(q1.y - q1.x) + fabsf(q1.z - q1.y) + fabsf(q1.w - q1.z)
          + fabsf(q2.x - q1.w)
          + fabsf(q2.y - q2.x) + fabsf(q2.z - q2.y) + fabsf(q2.w - q2.z)
          + fabsf(q3.x - q2.w)
          + fabsf(q3.y - q3.x) + fabsf(q3.z - q3.y) + fabsf(q3.w - q3.z);
      const float nf = dpp_right(q0.x);
      if (tx < 15) sx += fabsf(nf - q3.w);
      if (r > 0) sy += ad4(q0, pr0) + ad4(q1, pr1) + ad4(q2, pr2) + ad4(q3, pr3);
      pr0 = q0; pr1 = q1; pr2 = q2; pr3 = q3;
      const float* grow = gb + (sr0 + r) * 256 + sc0;
      const float4 g0 = *(const float4*)(grow);
      const float4 g1 = *(const float4*)(grow + 4);
      const float4 g2 = *(const float4*)(grow + 8);
      const float4 g3 = *(const float4*)(grow + 12);
      const float u0 = (g0.x + g0.y) + (g0.z + g0.w);
      const float u1 = (g1.x + g1.y) + (g1.z + g1.w);
      const float u2 = (g2.x + g2.y) + (g2.z + g2.w);
      const float u3 = (g3.x + g3.y) + (g3.z + g3.w);
      c0 += u0; c1 += u1; c2 += u2; c3 += u3;
      sgraw += (u0 + u1) + (u2 + u3);
    }
    pd[i][0] = a0; pd[i][1] = a1; pd[i][2] = a2; pd[i][3] = a3;
    gd[i][0] = c0; gd[i][1] = c1; gd[i][2] = c2; gd[i][3] = c3;
  }
  if (tyg < 15) {
    const float* prow = pb + (sr0 + 16) * 256 + sc0;
    sy += ad4(*(const float4*)(prow), pr0) + ad4(*(const float4*)(prow + 4), pr1)
        + ad4(*(const float4*)(prow + 8), pr2) + ad4(*(const float4*)(prow + 12), pr3);
  }

  float spd = 0.f, sgd = 0.f;
#pragma unroll
  for (int i = 0; i < 4; ++i)
#pragma unroll
    for (int j = 0; j < 4; ++j) {
      pd[i][j] = fmaxf(pd[i][j] * 0.0625f, 0.f); spd += pd[i][j];
      gd[i][j] = fmaxf(gd[i][j] * 0.0625f, 0.f); sgd += gd[i][j];
    }

  float r0 = spraw, r1 = sgraw, r2 = spd, r3 = sgd, r4 = sx, r5 = sy;
#pragma unroll
  for (int o = 32; o > 0; o >>= 1) {
    r0 += __shfl_down(r0, o); r1 += __shfl_down(r1, o);
    r2 += __shfl_down(r2, o); r3 += __shfl_down(r3, o);
    r4 += __shfl_down(r4, o); r5 += __shfl_down(r5, o);
  }
  if ((t & 63) == 0) {
    const int w = t >> 6;
    rbuf[w * 6 + 0] = r0; rbuf[w * 6 + 1] = r1; rbuf[w * 6 + 2] = r2;
    rbuf[w * 6 + 3] = r3; rbuf[w * 6 + 4] = r4; rbuf[w * 6 + 5] = r5;
  }
  __syncthreads();
  if (t == 0) {
    float a0 = 0, a1 = 0, a2 = 0, a3 = 0, a4 = 0, a5 = 0;
    for (int w = 0; w < 4; ++w) {
      a0 += rbuf[w * 6 + 0]; a1 += rbuf[w * 6 + 1]; a2 += rbuf[w * 6 + 2];
      a3 += rbuf[w * 6 + 3]; a4 += rbuf[w * 6 + 4]; a5 += rbuf[w * 6 + 5];
    }
    ws[b] = a0; ws[16 + b] = a1; ws[48 + b] = a4; ws[64 + b] = a5;
    rbuf[0] = a2; rbuf[1] = a3;
  }
  __syncthreads();
  const float Sp = rbuf[0], Sg = rbuf[1];

  float av[4][4], bv[4][4];
#pragma unroll
  for (int i = 0; i < 4; ++i)
#pragma unroll
    for (int j = 0; j < 4; ++j) {
      av[i][j] = (Sp > 0.f) ? (pd[i][j] / Sp) : (1.f / 4096.f);
      bv[i][j] = (Sg > 0.f) ? (gd[i][j] / Sg) : (1.f / 4096.f);
    }

  const int rbb = tyg * RP2 + x0 + 2;
  const int rtb = (tyg + 2) * RP2 + x0 + 2;
  const int wb  = (1 + tyg) * RP2 + 4 + x0;

  float uu[4][4], vv[4][4], uh[4][4], vh[4][4];
#pragma unroll
  for (int i = 0; i < 4; ++i)
#pragma unroll
    for (int j = 0; j < 4; ++j) vv[i][j] = 1.f;
  *(float4*)&RTv[wb] = make_float4(1.f, 1.f, 1.f, 1.f);
  *(float4*)&RBv[wb] = make_float4(1.f, 1.f, 1.f, 1.f);
  __syncthreads();

#pragma unroll 1
  for (int it = 0; it < 50; ++it) {
    {
      const float2 mA = *(const float2*)&RBv[rbb];
      const float4 mB = *(const float4*)&RBv[rbb + 2];
      const float2 mC = *(const float2*)&RBv[rbb + 6];
      const float2 pA = *(const float2*)&RTv[rtb];
      const float4 pB = *(const float4*)&RTv[rtb + 2];
      const float2 pC = *(const float2*)&RTv[rtb + 6];
      if (it != 0) {
#pragma unroll
        for (int j = 0; j < 4; ++j) {
          vv[1][j] = bv[1][j] * __builtin_amdgcn_rcpf(fmaf(KW1, uh[0][j] + uh[2][j], uh[1][j]));
          vv[2][j] = bv[2][j] * __builtin_amdgcn_rcpf(fmaf(KW1, uh[1][j] + uh[3][j], uh[2][j]));
        }
      }
      phase_core(vv, vh, av[0], av[3], mA, mB, mC, pA, pB, pC,
                 RTu, RBu, wb, uu[0], uu[3]);
    }
    __syncthreads();
    {
      const float2 mA = *(const float2*)&RBu[rbb];
      const float4 mB = *(const float4*)&RBu[rbb + 2];
      const float2 mC = *(const float2*)&RBu[rbb + 6];
      const float2 pA = *(const float2*)&RTu[rtb];
      const float4 pB = *(const float4*)&RTu[rtb + 2];
      const float2 pC = *(const float2*)&RTu[rtb + 6];
#pragma unroll
      for (int j = 0; j < 4; ++j) {
        uu[1][j] = av[1][j] * __builtin_amdgcn_rcpf(fmaf(KW1, vh[0][j] + vh[2][j], vh[1][j]));
        uu[2][j] = av[2][j] * __builtin_amdgcn_rcpf(fmaf(KW1, vh[1][j] + vh[3][j], vh[2][j]));
      }
      phase_core(uu, uh, bv[0], bv[3], mA, mB, mC, pA, pB, pC,
                 RTv, RBv, wb, vv[0], vv[3]);
    }
    __syncthreads();
  }
#pragma unroll
  for (int j = 0; j < 4; ++j) {
    vv[1][j] = bv[1][j] * __builtin_amdgcn_rcpf(fmaf(KW1, uh[0][j] + uh[2][j], uh[1][j]));
    vv[2][j] = bv[2][j] * __builtin_amdgcn_rcpf(fmaf(KW1, uh[1][j] + uh[3][j], uh[2][j]));
  }

  float c = 0.f;
  {
    const float2 mA = *(const float2*)&RBv[rbb];
    const float4 mB = *(const float4*)&RBv[rbb + 2];
    const float2 mC = *(const float2*)&RBv[rbb + 6];
    const float2 pA = *(const float2*)&RTv[rtb];
    const float4 pB = *(const float4*)&RTv[rtb + 2];
    const float2 pC = *(const float2*)&RTv[rtb + 6];
    float W[6][6];
    W[0][0] = mA.y; W[0][1] = mB.x; W[0][2] = mB.y;
    W[0][3] = mB.z; W[0][4] = mB.w; W[0][5] = mC.x;
    W[5][0] = pA.y; W[5][1] = pB.x; W[5][2] = pB.y;
    W[5][3] = pB.z; W[5][4] = pB.w; W[5][5] = pC.x;
#pragma unroll
    for (int i = 0; i < 4; ++i) {
      W[1 + i][0] = dpp_left(vv[i][3]);
      W[1 + i][5] = dpp_right(vv[i][0]);
#pragma unroll
      for (int j = 0; j < 4; ++j) W[1 + i][1 + j] = vv[i][j];
    }
#pragma unroll
    for (int i = 0; i < 4; ++i)
#pragma unroll
      for (int j = 0; j < 4; ++j) {
        const float e = (W[i][j + 1] + W[i + 2][j + 1])
                      + (W[i + 1][j] + W[i + 1][j + 2]);
        const float d = (W[i][j] + W[i][j + 2])
                      + (W[i + 2][j] + W[i + 2][j + 2]);
        c += uu[i][j] * fmaf(MW2, d, KW1 * e);
      }
  }
#pragma unroll
  for (int o = 32; o > 0; o >>= 1) c += __shfl_down(c, o);
  if ((t & 63) == 0) rbuf[t >> 6] = c;
  __syncthreads();
  if (t == 0) {
    ws[32 + b] = rbuf[0] + rbuf[1] + rbuf[2] + rbuf[3];
    __threadfence();
    const unsigned int old = atomicAdd(cnt, 1u);
    if (old == 15u) {
      __threadfence();
      float lc = 0.f, lot = 0.f, tvx = 0.f, tvy = 0.f;
      for (int k = 0; k < 16; ++k) {
        const float p = agent_ld(&ws[k]);
        const float g = agent_ld(&ws[16 + k]);
        const float ct = agent_ld(&ws[32 + k]);
        const float x = agent_ld(&ws[48 + k]);
        const float y = agent_ld(&ws[64 + k]);
        lc += fabsf(p - g); lot += ct; tvx += x; tvy += y;
      }
      int me = max_epoch[0]; if (me < 1) me = 1;
      const float tt = (float)epoch[0] / (float)me;
      const float ltv = tvx / (16.f * 256.f * 255.f) + tvy / (16.f * 255.f * 256.f);
      out[0] = lc * (1.f / 16.f) + tt * (lot * (1.f / 16.f)) + tt * ltv;
    }
  }
}

extern "C" void kernel_launch(void* const* d_in, const int* in_sizes, int n_in,
                              void* d_out, int out_size, void* d_ws, size_t ws_size,
                              hipStream_t stream) {
  const float* pred = (const float*)d_in[0];
  const float* gt   = (const float*)d_in[1];
  const int* epoch  = (const int*)d_in[2];
  const int* max_ep = (const int*)d_in[3];
  float* out = (float*)d_out;
  float* ws  = (float*)d_ws;

  if (ws_size >= 600000) {
    unsigned int* cnt = (unsigned int*)((char*)d_ws + 4160);
    prep_kernel<<<dim3(256), dim3(256), 0, stream>>>(pred, gt, ws, cnt);
    sink_kernel<<<dim3(16), dim3(1024), 0, stream>>>(ws, epoch, max_ep, out, cnt);
  } else {
    unsigned int* cnt = (unsigned int*)((char*)d_ws + 384);
    hipMemsetAsync(cnt, 0, 4, stream);
    fused_fallback<<<dim3(16), dim3(256), 0, stream>>>(pred, gt, ws, epoch,
                                                       max_ep, out, cnt);
  }
}